// Round 3
// baseline (1948.056 us; speedup 1.0000x reference)
//
#include <hip/hip_runtime.h>
#include <cstddef>

#define TT 1024
#define BB 16384
#define LC 32
#define CC (TT / LC)

typedef float v2f __attribute__((ext_vector_type(2)));

__device__ __forceinline__ v2f splat2(float x) { v2f r; r.x = x; r.y = x; return r; }

#if __has_builtin(__builtin_amdgcn_exp2f)
#define EXP2F(x) __builtin_amdgcn_exp2f(x)
#else
#define EXP2F(x) __expf((x) * 0.6931471805599453f)
#endif

// tanh(x) = 1 - 2/(2^(x*2*log2e) + 1). Saturates exactly at +-1 for large |x|
// (exp2 -> inf -> rcp -> 0), so no clamp needed. ~1 ulp exp + rcp: |err| ~1e-6.
__device__ __forceinline__ v2f tanh2(v2f x) {
    v2f y = x * 2.885390081777927f;  // 2*log2(e)
    float ex = EXP2F(y.x);
    float ey = EXP2F(y.y);
    v2f r;
    r.x = __builtin_amdgcn_rcpf(ex + 1.0f);
    r.y = __builtin_amdgcn_rcpf(ey + 1.0f);
    return __builtin_elementwise_fma(splat2(-2.0f), r, splat2(1.0f));
}

// Phase 1: per (chunk c, batch b) run the affine recurrence from zero state,
// store the chunk offset v[c][i][b]  (layout [C][6][B] for coalescing).
__global__ __launch_bounds__(256) void k_phase1(
    const float* __restrict__ targets,
    const float* __restrict__ Wx,
    const float* __restrict__ Wu,
    float* __restrict__ v)
{
    const int b = blockIdx.x * 256 + threadIdx.x;
    const int c = blockIdx.y;
    float wx[6][6], wu[6];
#pragma unroll
    for (int i = 0; i < 6; ++i) {
        wu[i] = Wu[i];
#pragma unroll
        for (int j = 0; j < 6; ++j) wx[i][j] = Wx[i * 6 + j];
    }
    float db[6] = {0.f, 0.f, 0.f, 0.f, 0.f, 0.f};
    const int t0 = c * LC;
#pragma unroll 4
    for (int s = 0; s < LC; ++s) {
        const int t = t0 + s;
        float u = 0.0f;
        if (t > 0) u = targets[(size_t)(t - 1) * BB + b];
        float nd[6];
#pragma unroll
        for (int i = 0; i < 6; ++i) {
            float a = u * wu[i];
#pragma unroll
            for (int j = 0; j < 6; ++j) a = fmaf(db[j], wx[i][j], a);
            nd[i] = a;
        }
#pragma unroll
        for (int i = 0; i < 6; ++i) db[i] = nd[i];
    }
#pragma unroll
    for (int i = 0; i < 6; ++i) v[((size_t)c * 6 + i) * BB + b] = db[i];
}

// Phase 2: per batch b, sequential prefix over the 32 chunks.
// db_start[c+1] = db_start[c] * M + v[c],  M = (Wx^T)^32 (5 squarings).
// In-place: v[c][.][b] is replaced by db_start[c][.][b].
__global__ __launch_bounds__(256) void k_phase2(
    const float* __restrict__ Wx,
    float* __restrict__ v)
{
    const int b = blockIdx.x * 256 + threadIdx.x;
    float M[6][6];
#pragma unroll
    for (int i = 0; i < 6; ++i)
#pragma unroll
        for (int j = 0; j < 6; ++j)
            M[j][i] = Wx[i * 6 + j];  // N = Wx^T in row-vector convention
    for (int it = 0; it < 5; ++it) {
        float P[6][6];
#pragma unroll
        for (int i = 0; i < 6; ++i)
#pragma unroll
            for (int j = 0; j < 6; ++j) {
                float a = 0.0f;
#pragma unroll
                for (int k = 0; k < 6; ++k) a = fmaf(M[i][k], M[k][j], a);
                P[i][j] = a;
            }
#pragma unroll
        for (int i = 0; i < 6; ++i)
#pragma unroll
            for (int j = 0; j < 6; ++j) M[i][j] = P[i][j];
    }
    float db[6] = {0.f, 0.f, 0.f, 0.f, 0.f, 0.f};
    for (int c = 0; c < CC; ++c) {
        float vv[6];
#pragma unroll
        for (int i = 0; i < 6; ++i) {
            const size_t idx = ((size_t)c * 6 + i) * BB + b;
            vv[i] = v[idx];
            v[idx] = db[i];  // overwrite with the start state for chunk c
        }
        float nd[6];
#pragma unroll
        for (int i = 0; i < 6; ++i) {
            float a = vv[i];
#pragma unroll
            for (int j = 0; j < 6; ++j) a = fmaf(db[j], M[j][i], a);
            nd[i] = a;
        }
#pragma unroll
        for (int i = 0; i < 6; ++i) db[i] = nd[i];
    }
}

// Phase 3 v3: lane pairs split the 20 hidden units 10/10 (W1-half = 120 VGPRs),
// and each lane carries TWO batch columns as float2 -> v_pk_fma_f32 (2 MACs/
// instr) for recurrence, layer 1, and the output dot. tanh via exp2+rcp, no
// clamp. Wave covers 64 (t,b) elements per step.
__global__ __launch_bounds__(256, 2) void k_phase3(
    const float* __restrict__ inputs,
    const float* __restrict__ targets,
    const float* __restrict__ Wxg,
    const float* __restrict__ Wug,
    const float* __restrict__ W1g,
    const float* __restrict__ b1g,
    const float* __restrict__ W2g,
    const float* __restrict__ b2g,
    const float* __restrict__ dbs,
    float* __restrict__ out)
{
    const int tid  = threadIdx.x;
    const int half = tid & 1;
    const int pair = tid >> 1;
    const int col  = blockIdx.x * 256 + pair * 2;  // this lane's 2 batch columns
    const int c    = blockIdx.y;
    const int m0   = half * 10;

    // Wave-uniform weights -> scalar loads / SGPRs.
    float wx[6][6], wu[6];
#pragma unroll
    for (int i = 0; i < 6; ++i) {
        wu[i] = Wug[i];
#pragma unroll
        for (int j = 0; j < 6; ++j) wx[i][j] = Wxg[i * 6 + j];
    }
    const float vb2 = b2g[0];

    // Per-half weights: 10 hidden units.
    float w1[10][12], vb1[10], vw2[10];
#pragma unroll
    for (int m = 0; m < 10; ++m) {
#pragma unroll
        for (int j = 0; j < 12; ++j) w1[m][j] = W1g[(m0 + m) * 12 + j];
        vb1[m] = b1g[m0 + m];
        vw2[m] = W2g[m0 + m];
    }

    v2f db[6];
#pragma unroll
    for (int i = 0; i < 6; ++i)
        db[i] = *(const v2f*)&dbs[((size_t)c * 6 + i) * BB + col];

    const int t0 = c * LC;
    v2f u_cur = splat2(0.0f);
    if (t0 > 0) u_cur = *(const v2f*)&targets[(size_t)(t0 - 1) * BB + col];
    // 12 contiguous floats = x[col][0..5], x[col+1][0..5]; 48B-multiple offset
    // -> three aligned float4 loads.
    const float4* xp = (const float4*)(inputs + ((size_t)t0 * BB + col) * 6);
    float4 a0 = xp[0], a1 = xp[1], a2 = xp[2];

    for (int s = 0; s < LC; ++s) {
        const int t = t0 + s;
        // Prefetch next step's inputs (addresses independent of recurrence).
        v2f u_nxt = splat2(0.0f);
        float4 p0 = a0, p1 = a1, p2 = a2;
        if (s + 1 < LC) {
            u_nxt = *(const v2f*)&targets[(size_t)t * BB + col];  // (t+1)-1 = t
            const float4* xpn =
                (const float4*)(inputs + ((size_t)(t + 1) * BB + col) * 6);
            p0 = xpn[0]; p1 = xpn[1]; p2 = xpn[2];
        }

        // Delay-buffer update, packed over the 2 columns.
        v2f nd[6];
#pragma unroll
        for (int i = 0; i < 6; ++i) {
            v2f a = u_cur * wu[i];
#pragma unroll
            for (int j = 0; j < 6; ++j)
                a = __builtin_elementwise_fma(db[j], splat2(wx[i][j]), a);
            nd[i] = a;
        }
#pragma unroll
        for (int i = 0; i < 6; ++i) db[i] = nd[i];

        // ni[j] = {col0[j], col1[j]}
        v2f ni[12];
#pragma unroll
        for (int i = 0; i < 6; ++i) ni[i] = db[i];
        ni[6].x  = a0.x; ni[6].y  = a1.z;
        ni[7].x  = a0.y; ni[7].y  = a1.w;
        ni[8].x  = a0.z; ni[8].y  = a2.x;
        ni[9].x  = a0.w; ni[9].y  = a2.y;
        ni[10].x = a1.x; ni[10].y = a2.z;
        ni[11].x = a1.y; ni[11].y = a2.w;

        // Layer 1 for my 10 units (pk fma: weight broadcast x 2 columns).
        v2f acc[10];
#pragma unroll
        for (int m = 0; m < 10; ++m) acc[m] = splat2(vb1[m]);
#pragma unroll
        for (int j = 0; j < 12; ++j) {
            const v2f nij = ni[j];
#pragma unroll
            for (int m = 0; m < 10; ++m)
                acc[m] = __builtin_elementwise_fma(splat2(w1[m][j]), nij, acc[m]);
        }

        // tanh + partial output over my 10 units.
        v2f osum = splat2(0.0f);
#pragma unroll
        for (int m = 0; m < 10; ++m)
            osum = __builtin_elementwise_fma(splat2(vw2[m]), tanh2(acc[m]), osum);

        // Combine the two halves of the lane pair.
        v2f other;
        other.x = __shfl_xor(osum.x, 1, 64);
        other.y = __shfl_xor(osum.y, 1, 64);
        v2f o = osum + other + splat2(vb2);
        if (half == 0) {
            float2 st; st.x = o.x; st.y = o.y;
            *(float2*)&out[(size_t)t * BB + col] = st;
        }

        u_cur = u_nxt; a0 = p0; a1 = p1; a2 = p2;
    }
}

extern "C" void kernel_launch(void* const* d_in, const int* in_sizes, int n_in,
                              void* d_out, int out_size, void* d_ws, size_t ws_size,
                              hipStream_t stream) {
    (void)in_sizes; (void)n_in; (void)out_size; (void)ws_size;
    const float* inputs  = (const float*)d_in[0];
    const float* targets = (const float*)d_in[1];
    const float* Wx = (const float*)d_in[2];
    const float* Wu = (const float*)d_in[3];
    const float* W1 = (const float*)d_in[4];
    const float* b1 = (const float*)d_in[5];
    const float* W2 = (const float*)d_in[6];
    const float* b2 = (const float*)d_in[7];
    float* out = (float*)d_out;
    float* v   = (float*)d_ws;  // needs CC*6*BB*4 = 12.6 MB of workspace

    dim3 blk(256);
    dim3 g1(BB / 256, CC);
    hipLaunchKernelGGL(k_phase1, g1, blk, 0, stream, targets, Wx, Wu, v);
    hipLaunchKernelGGL(k_phase2, dim3(BB / 256), blk, 0, stream, Wx, v);
    dim3 g3(BB / 256, CC);  // 256 threads = 128 pairs = 256 columns per block
    hipLaunchKernelGGL(k_phase3, g3, blk, 0, stream,
                       inputs, targets, Wx, Wu, W1, b1, W2, b2, v, out);
}